// Round 1
// baseline (88.632 us; speedup 1.0000x reference)
//
#include <hip/hip_runtime.h>
#include <math.h>

// Cox partial likelihood NLL.
// loss = -(1/n) * sum_i e_i * (risk_i - log(P[time_i]))
//   where P[t] = sum_{t' <= t} S[t'],  S[t] = sum_{time_j = t} exp(risk_j)
// Decompose: A = sum_i e_i*risk_i ; B = sum_t E[t]*log(P[t]), E[t] = sum_{time_j=t} e_j
// loss = -(A - B)/n

#define TMAXV   100000
#define NPAD    100352          // 98 * 1024, padded bucket count
#define NBLK_SC 98

// Block reduce (supports up to 16 waves / 1024 threads). Result valid in
// lane 0 of wave 0 only. lds must hold >= 16 floats.
__device__ __forceinline__ float block_reduce_sum(float v, float* lds) {
    const int lane = threadIdx.x & 63;
    const int wid  = threadIdx.x >> 6;
    #pragma unroll
    for (int d = 32; d > 0; d >>= 1) v += __shfl_down(v, d);
    __syncthreads();                     // protect lds from previous use
    if (lane == 0) lds[wid] = v;
    __syncthreads();
    float r = 0.f;
    if (wid == 0) {
        const int nw = (int)(blockDim.x >> 6);
        r = (lane < nw) ? lds[lane] : 0.f;
        #pragma unroll
        for (int d = 8; d > 0; d >>= 1) r += __shfl_down(r, d);
    }
    return r;
}

// K1: bucket-accumulate S[t] += exp(risk), E[t] += e, and A += e*risk.
// time is sorted ascending, so each 64-lane wave step covers a handful of
// runs; wave-segmented scan + one atomic per run-piece avoids ~64-way
// same-address atomic serialization.
__global__ __launch_bounds__(256)
void k1_bucket(const float* __restrict__ risk, const float* __restrict__ ev,
               const int* __restrict__ tim,
               float* __restrict__ S, float* __restrict__ E,
               float* __restrict__ A, int n, int per_block) {
    __shared__ float lds[16];
    const int lane  = threadIdx.x & 63;
    const int start = (int)blockIdx.x * per_block;
    int end = start + per_block;
    if (end > n) end = n;

    float accA = 0.f;
    for (int i0 = start; i0 < end; i0 += (int)blockDim.x) {
        const int  i     = i0 + (int)threadIdx.x;
        const bool valid = (i < end);
        float v = 0.f, w = 0.f;
        int   t = 0x7fffffff;            // sentinel: never flushed (guarded)
        if (valid) {
            const float rk = risk[i];
            v = expf(rk);
            w = ev[i];
            t = tim[i];
            accA += w * rk;
        }
        // segmented inclusive scan across the wave, keyed by t
        float sv = v, sw = w;
        #pragma unroll
        for (int d = 1; d < 64; d <<= 1) {
            float ov = __shfl_up(sv, d);
            float ow = __shfl_up(sw, d);
            int   ot = __shfl_up(t, d);
            if (lane >= d && ot == t) { sv += ov; sw += ow; }
        }
        const int nt = __shfl_down(t, 1);
        if (valid && (lane == 63 || nt != t)) {  // end of run-piece -> flush
            atomicAdd(&S[t], sv);
            atomicAdd(&E[t], sw);
        }
    }
    const float tot = block_reduce_sum(accA, lds);
    if (threadIdx.x == 0) atomicAdd(A, tot);
}

// K2: per-1024-chunk partial sums of S.
__global__ __launch_bounds__(256)
void k2_partials(const float* __restrict__ S, float* __restrict__ partials) {
    __shared__ float lds[16];
    const int base = (int)blockIdx.x * 1024;
    float v = 0.f;
    for (int j = (int)threadIdx.x; j < 1024; j += 256) v += S[base + j];
    const float tot = block_reduce_sum(v, lds);
    if (threadIdx.x == 0) partials[blockIdx.x] = tot;
}

// K3: per-chunk inclusive scan of S (+offset from preceding partials),
// then dot with E via log(P). Accumulate into B.
__global__ __launch_bounds__(1024)
void k3_scan_dot(const float* __restrict__ S, const float* __restrict__ E,
                 const float* __restrict__ partials, float* __restrict__ Bacc) {
    __shared__ float lds[16];
    __shared__ float wsum[16];
    __shared__ float s_off;
    const int tid  = (int)threadIdx.x;
    const int lane = tid & 63;
    const int wid  = tid >> 6;
    const int base = (int)blockIdx.x * 1024;

    // offset = sum of partials[0 .. blockIdx-1] (<= 97 values, redundant per block)
    float p = (tid < (int)blockIdx.x) ? partials[tid] : 0.f;
    const float off = block_reduce_sum(p, lds);
    if (tid == 0) s_off = off;
    __syncthreads();
    const float offset = s_off;

    // block inclusive scan of 1024 S values
    const float x = S[base + tid];
    float s = x;
    #pragma unroll
    for (int d = 1; d < 64; d <<= 1) {
        const float o = __shfl_up(s, d);
        if (lane >= d) s += o;
    }
    if (lane == 63) wsum[wid] = s;
    __syncthreads();
    if (wid == 0) {
        float ws = (lane < 16) ? wsum[lane] : 0.f;
        #pragma unroll
        for (int d = 1; d < 16; d <<= 1) {
            const float o = __shfl_up(ws, d);
            if (lane >= d) ws += o;
        }
        if (lane < 16) wsum[lane] = ws;
    }
    __syncthreads();
    const float incl = s + (wid > 0 ? wsum[wid - 1] : 0.f);
    const float P = offset + incl;

    const float w = E[base + tid];
    const float c = (w != 0.f) ? w * logf(P) : 0.f;  // E>0 => bucket nonempty => P>0
    const float tot = block_reduce_sum(c, lds);
    if (tid == 0) atomicAdd(Bacc, tot);
}

__global__ void k4_final(const float* __restrict__ A, const float* __restrict__ B,
                         float* __restrict__ out, float inv_n) {
    out[0] = -(A[0] - B[0]) * inv_n;
}

extern "C" void kernel_launch(void* const* d_in, const int* in_sizes, int n_in,
                              void* d_out, int out_size, void* d_ws, size_t ws_size,
                              hipStream_t stream) {
    const float* risk = (const float*)d_in[0];
    const float* ev   = (const float*)d_in[1];
    const int*   tim  = (const int*)d_in[2];
    float* out = (float*)d_out;
    const int n = in_sizes[0];

    // workspace layout (floats): S[NPAD] | E[NPAD] | partials[128] | A | B
    float* S        = (float*)d_ws;
    float* E        = S + NPAD;
    float* partials = E + NPAD;
    float* A        = partials + 128;
    float* B        = A + 1;

    hipMemsetAsync(d_ws, 0, (size_t)(2 * NPAD + 130) * sizeof(float), stream);

    const int blocks = 2048, threads = 256;
    int per_block = (n + blocks - 1) / blocks;
    per_block = ((per_block + threads - 1) / threads) * threads;  // wave-aligned

    hipLaunchKernelGGL(k1_bucket, dim3(blocks), dim3(threads), 0, stream,
                       risk, ev, tim, S, E, A, n, per_block);
    hipLaunchKernelGGL(k2_partials, dim3(NBLK_SC), dim3(256), 0, stream, S, partials);
    hipLaunchKernelGGL(k3_scan_dot, dim3(NBLK_SC), dim3(1024), 0, stream, S, E, partials, B);
    hipLaunchKernelGGL(k4_final, dim3(1), dim3(1), 0, stream, A, B, out, 1.0f / (float)n);
}

// Round 2
// 64.686 us; speedup vs baseline: 1.3702x; 1.3702x over previous
//
#include <hip/hip_runtime.h>
#include <math.h>

// Cox partial likelihood NLL.
// loss = -(1/n) * sum_i e_i * (risk_i - log(P[time_i]))
//   where P[t] = sum_{t' <= t} S[t'],  S[t] = sum_{time_j = t} exp(risk_j)
// Decompose: A = sum_i e_i*risk_i ; B = sum_t E[t]*log(P[t]), E[t] = sum_{time_j=t} e_j
// loss = -(A - B)/n
//
// K1 processes 8 contiguous elements per thread (coalesced float4 pairs).
// Within-thread runs are handled sequentially (times sorted ascending);
// cross-lane run carry uses one 6-step segmented scan per 512 elements
// (vs per 64 previously) -- DS/shuffle pipe cost drops ~6.5x.

#define TMAXV   100000
#define NPAD    100352          // 98 * 1024, padded bucket count
#define NBLK_SC 98
#define VPT     8               // elements per thread per window
#define SENT    0x7fffffff      // sentinel time for invalid lanes (never flushed)

// Block reduce (up to 16 waves). Result valid in lane 0 of wave 0 only.
__device__ __forceinline__ float block_reduce_sum(float v, float* lds) {
    const int lane = threadIdx.x & 63;
    const int wid  = threadIdx.x >> 6;
    #pragma unroll
    for (int d = 32; d > 0; d >>= 1) v += __shfl_down(v, d);
    __syncthreads();
    if (lane == 0) lds[wid] = v;
    __syncthreads();
    float r = 0.f;
    if (wid == 0) {
        const int nw = (int)(blockDim.x >> 6);
        r = (lane < nw) ? lds[lane] : 0.f;
        #pragma unroll
        for (int d = 8; d > 0; d >>= 1) r += __shfl_down(r, d);
    }
    return r;
}

__global__ __launch_bounds__(256)
void k1_bucket(const float* __restrict__ risk, const float* __restrict__ ev,
               const int* __restrict__ tim,
               float* __restrict__ S, float* __restrict__ E,
               float* __restrict__ A, int n, int per_block) {
    __shared__ float lds[16];
    const int lane  = threadIdx.x & 63;
    const int start = (int)blockIdx.x * per_block;
    int end = start + per_block;
    if (end > n) end = n;
    const int step = (int)blockDim.x * VPT;

    float accA = 0.f;
    for (int i0 = start; i0 < end; i0 += step) {
        const int base = i0 + (int)threadIdx.x * VPT;  // this thread's 8-elem strip
        float r[VPT], w[VPT];
        int   t[VPT];
        if (base + VPT <= end) {
            const float4 ra = *(const float4*)(risk + base);
            const float4 rb = *(const float4*)(risk + base + 4);
            const float4 wa = *(const float4*)(ev + base);
            const float4 wb = *(const float4*)(ev + base + 4);
            const int4   ta = *(const int4*)(tim + base);
            const int4   tb = *(const int4*)(tim + base + 4);
            r[0]=ra.x; r[1]=ra.y; r[2]=ra.z; r[3]=ra.w;
            r[4]=rb.x; r[5]=rb.y; r[6]=rb.z; r[7]=rb.w;
            w[0]=wa.x; w[1]=wa.y; w[2]=wa.z; w[3]=wa.w;
            w[4]=wb.x; w[5]=wb.y; w[6]=wb.z; w[7]=wb.w;
            t[0]=ta.x; t[1]=ta.y; t[2]=ta.z; t[3]=ta.w;
            t[4]=tb.x; t[5]=tb.y; t[6]=tb.z; t[7]=tb.w;
        } else {
            #pragma unroll
            for (int j = 0; j < VPT; ++j) {
                const int i = base + j;
                const bool ok = (i < end);
                r[j] = ok ? risk[i] : 0.f;
                w[j] = ok ? ev[i]   : 0.f;
                t[j] = ok ? tim[i]  : SENT;
            }
        }

        float ve[VPT];
        #pragma unroll
        for (int j = 0; j < VPT; ++j) {
            ve[j] = __expf(r[j]);
            accA += w[j] * r[j];          // w==0 for invalid lanes
        }

        // trailing-run sums (times sorted => equality to tail is contiguous)
        const int head_t = t[0];
        const int tail_t = t[VPT - 1];
        float tsv = 0.f, tsw = 0.f;
        #pragma unroll
        for (int j = 0; j < VPT; ++j) {
            if (t[j] == tail_t) { tsv += ve[j]; tsw += w[j]; }
        }

        // cross-lane segmented inclusive scan of trailing sums, keyed on tail_t
        float Sv = tsv, Sw = tsw;
        #pragma unroll
        for (int d = 1; d < 64; d <<= 1) {
            const float ov = __shfl_up(Sv, d);
            const float ow = __shfl_up(Sw, d);
            const int   ok = __shfl_up(tail_t, d);
            if (lane >= d && ok == tail_t) { Sv += ov; Sw += ow; }
        }

        // carry into this thread's head run (exact under sortedness)
        float cv = 0.f, cw = 0.f;
        {
            const float pv = __shfl_up(Sv, 1);
            const float pw = __shfl_up(Sw, 1);
            const int   pk = __shfl_up(tail_t, 1);
            if (lane > 0 && pk == head_t) { cv = pv; cw = pw; }
        }

        // per-thread sequential run pass, flushing closed runs
        int   cur_t = head_t;
        float cur_v = cv, cur_w = cw;
        #pragma unroll
        for (int j = 0; j < VPT; ++j) {
            if (t[j] != cur_t) {
                if (cur_t != SENT) {
                    atomicAdd(&S[cur_t], cur_v);
                    atomicAdd(&E[cur_t], cur_w);
                }
                cur_t = t[j]; cur_v = 0.f; cur_w = 0.f;
            }
            cur_v += ve[j]; cur_w += w[j];
        }
        // trailing run: flush only if it does not continue into the next lane
        const int nh = __shfl_down(head_t, 1);
        if ((lane == 63 || nh != tail_t) && cur_t != SENT) {
            atomicAdd(&S[cur_t], cur_v);
            atomicAdd(&E[cur_t], cur_w);
        }
    }

    const float tot = block_reduce_sum(accA, lds);
    if (threadIdx.x == 0) atomicAdd(A, tot);
}

// K2: per-1024-chunk partial sums of S.
__global__ __launch_bounds__(256)
void k2_partials(const float* __restrict__ S, float* __restrict__ partials) {
    __shared__ float lds[16];
    const int base = (int)blockIdx.x * 1024;
    float v = 0.f;
    for (int j = (int)threadIdx.x; j < 1024; j += 256) v += S[base + j];
    const float tot = block_reduce_sum(v, lds);
    if (threadIdx.x == 0) partials[blockIdx.x] = tot;
}

// K3: per-chunk inclusive scan of S (+offset), dot with E via log(P) -> B.
__global__ __launch_bounds__(1024)
void k3_scan_dot(const float* __restrict__ S, const float* __restrict__ E,
                 const float* __restrict__ partials, float* __restrict__ Bacc) {
    __shared__ float lds[16];
    __shared__ float wsum[16];
    __shared__ float s_off;
    const int tid  = (int)threadIdx.x;
    const int lane = tid & 63;
    const int wid  = tid >> 6;
    const int base = (int)blockIdx.x * 1024;

    float p = (tid < (int)blockIdx.x) ? partials[tid] : 0.f;
    const float off = block_reduce_sum(p, lds);
    if (tid == 0) s_off = off;
    __syncthreads();
    const float offset = s_off;

    const float x = S[base + tid];
    float s = x;
    #pragma unroll
    for (int d = 1; d < 64; d <<= 1) {
        const float o = __shfl_up(s, d);
        if (lane >= d) s += o;
    }
    if (lane == 63) wsum[wid] = s;
    __syncthreads();
    if (wid == 0) {
        float ws = (lane < 16) ? wsum[lane] : 0.f;
        #pragma unroll
        for (int d = 1; d < 16; d <<= 1) {
            const float o = __shfl_up(ws, d);
            if (lane >= d) ws += o;
        }
        if (lane < 16) wsum[lane] = ws;
    }
    __syncthreads();
    const float incl = s + (wid > 0 ? wsum[wid - 1] : 0.f);
    const float P = offset + incl;

    const float w = E[base + tid];
    const float c = (w != 0.f) ? w * __logf(P) : 0.f;
    const float tot = block_reduce_sum(c, lds);
    if (tid == 0) atomicAdd(Bacc, tot);
}

__global__ void k4_final(const float* __restrict__ A, const float* __restrict__ B,
                         float* __restrict__ out, float inv_n) {
    out[0] = -(A[0] - B[0]) * inv_n;
}

extern "C" void kernel_launch(void* const* d_in, const int* in_sizes, int n_in,
                              void* d_out, int out_size, void* d_ws, size_t ws_size,
                              hipStream_t stream) {
    const float* risk = (const float*)d_in[0];
    const float* ev   = (const float*)d_in[1];
    const int*   tim  = (const int*)d_in[2];
    float* out = (float*)d_out;
    const int n = in_sizes[0];

    // workspace layout (floats): S[NPAD] | E[NPAD] | partials[128] | A | B
    float* S        = (float*)d_ws;
    float* E        = S + NPAD;
    float* partials = E + NPAD;
    float* A        = partials + 128;
    float* B        = A + 1;

    hipMemsetAsync(d_ws, 0, (size_t)(2 * NPAD + 130) * sizeof(float), stream);

    const int blocks = 2048, threads = 256;
    const int win = threads * VPT;                     // 2048 elements per block-iter
    int per_block = (n + blocks - 1) / blocks;
    per_block = ((per_block + win - 1) / win) * win;   // window-aligned

    hipLaunchKernelGGL(k1_bucket, dim3(blocks), dim3(threads), 0, stream,
                       risk, ev, tim, S, E, A, n, per_block);
    hipLaunchKernelGGL(k2_partials, dim3(NBLK_SC), dim3(256), 0, stream, S, partials);
    hipLaunchKernelGGL(k3_scan_dot, dim3(NBLK_SC), dim3(1024), 0, stream, S, E, partials, B);
    hipLaunchKernelGGL(k4_final, dim3(1), dim3(1), 0, stream, A, B, out, 1.0f / (float)n);
}

// Round 3
// 64.681 us; speedup vs baseline: 1.3703x; 1.0001x over previous
//
#include <hip/hip_runtime.h>
#include <math.h>

// Cox partial likelihood NLL.
// loss = -(1/n) * sum_i e_i * (risk_i - log(P[time_i]))
//   where P[t] = sum_{t' <= t} S[t'],  S[t] = sum_{time_j = t} exp(risk_j)
// Decompose: A = sum_i e_i*risk_i ; B = sum_t E[t]*log(P[t]), E[t] = sum_{time_j=t} e_j
// loss = -(A - B)/n
//
// K1: 8 contiguous elements/thread (coalesced float4 pairs); per-thread run
// handling sequential; one 6-step cross-lane segmented scan per 512 elements.
// All f32 atomics are native global_atomic_add_f32 via unsafeAtomicAdd --
// plain atomicAdd(float*) compiles to a CAS loop (vmcnt-waited, on the wave
// critical path) without -munsafe-fp-atomics.

#define TMAXV   100000
#define NPAD    100352          // 98 * 1024, padded bucket count
#define NBLK_SC 98
#define VPT     8               // elements per thread per window
#define SENT    0x7fffffff      // sentinel time for invalid lanes (never flushed)

// Native f32 atomic add (fire-and-forget, no CAS loop).
__device__ __forceinline__ void atomAddF(float* p, float v) {
    unsafeAtomicAdd(p, v);
}

// Block reduce (up to 16 waves). Result valid in lane 0 of wave 0 only.
__device__ __forceinline__ float block_reduce_sum(float v, float* lds) {
    const int lane = threadIdx.x & 63;
    const int wid  = threadIdx.x >> 6;
    #pragma unroll
    for (int d = 32; d > 0; d >>= 1) v += __shfl_down(v, d);
    __syncthreads();
    if (lane == 0) lds[wid] = v;
    __syncthreads();
    float r = 0.f;
    if (wid == 0) {
        const int nw = (int)(blockDim.x >> 6);
        r = (lane < nw) ? lds[lane] : 0.f;
        #pragma unroll
        for (int d = 8; d > 0; d >>= 1) r += __shfl_down(r, d);
    }
    return r;
}

__global__ __launch_bounds__(256)
void k1_bucket(const float* __restrict__ risk, const float* __restrict__ ev,
               const int* __restrict__ tim,
               float* __restrict__ S, float* __restrict__ E,
               float* __restrict__ A, int n, int per_block) {
    __shared__ float lds[16];
    const int lane  = threadIdx.x & 63;
    const int start = (int)blockIdx.x * per_block;
    int end = start + per_block;
    if (end > n) end = n;
    const int step = (int)blockDim.x * VPT;

    float accA = 0.f;
    for (int i0 = start; i0 < end; i0 += step) {
        const int base = i0 + (int)threadIdx.x * VPT;  // this thread's 8-elem strip
        float r[VPT], w[VPT];
        int   t[VPT];
        if (base + VPT <= end) {
            const float4 ra = *(const float4*)(risk + base);
            const float4 rb = *(const float4*)(risk + base + 4);
            const float4 wa = *(const float4*)(ev + base);
            const float4 wb = *(const float4*)(ev + base + 4);
            const int4   ta = *(const int4*)(tim + base);
            const int4   tb = *(const int4*)(tim + base + 4);
            r[0]=ra.x; r[1]=ra.y; r[2]=ra.z; r[3]=ra.w;
            r[4]=rb.x; r[5]=rb.y; r[6]=rb.z; r[7]=rb.w;
            w[0]=wa.x; w[1]=wa.y; w[2]=wa.z; w[3]=wa.w;
            w[4]=wb.x; w[5]=wb.y; w[6]=wb.z; w[7]=wb.w;
            t[0]=ta.x; t[1]=ta.y; t[2]=ta.z; t[3]=ta.w;
            t[4]=tb.x; t[5]=tb.y; t[6]=tb.z; t[7]=tb.w;
        } else {
            #pragma unroll
            for (int j = 0; j < VPT; ++j) {
                const int i = base + j;
                const bool ok = (i < end);
                r[j] = ok ? risk[i] : 0.f;
                w[j] = ok ? ev[i]   : 0.f;
                t[j] = ok ? tim[i]  : SENT;
            }
        }

        float ve[VPT];
        #pragma unroll
        for (int j = 0; j < VPT; ++j) {
            ve[j] = __expf(r[j]);
            accA += w[j] * r[j];          // w==0 for invalid lanes
        }

        // trailing-run sums (times sorted => equality to tail is contiguous)
        const int head_t = t[0];
        const int tail_t = t[VPT - 1];
        float tsv = 0.f, tsw = 0.f;
        #pragma unroll
        for (int j = 0; j < VPT; ++j) {
            if (t[j] == tail_t) { tsv += ve[j]; tsw += w[j]; }
        }

        // cross-lane segmented inclusive scan of trailing sums, keyed on tail_t
        float Sv = tsv, Sw = tsw;
        #pragma unroll
        for (int d = 1; d < 64; d <<= 1) {
            const float ov = __shfl_up(Sv, d);
            const float ow = __shfl_up(Sw, d);
            const int   ok = __shfl_up(tail_t, d);
            if (lane >= d && ok == tail_t) { Sv += ov; Sw += ow; }
        }

        // carry into this thread's head run (exact under sortedness)
        float cv = 0.f, cw = 0.f;
        {
            const float pv = __shfl_up(Sv, 1);
            const float pw = __shfl_up(Sw, 1);
            const int   pk = __shfl_up(tail_t, 1);
            if (lane > 0 && pk == head_t) { cv = pv; cw = pw; }
        }

        // per-thread sequential run pass, flushing closed runs
        int   cur_t = head_t;
        float cur_v = cv, cur_w = cw;
        #pragma unroll
        for (int j = 0; j < VPT; ++j) {
            if (t[j] != cur_t) {
                if (cur_t != SENT) {
                    atomAddF(&S[cur_t], cur_v);
                    atomAddF(&E[cur_t], cur_w);
                }
                cur_t = t[j]; cur_v = 0.f; cur_w = 0.f;
            }
            cur_v += ve[j]; cur_w += w[j];
        }
        // trailing run: flush only if it does not continue into the next lane
        const int nh = __shfl_down(head_t, 1);
        if ((lane == 63 || nh != tail_t) && cur_t != SENT) {
            atomAddF(&S[cur_t], cur_v);
            atomAddF(&E[cur_t], cur_w);
        }
    }

    const float tot = block_reduce_sum(accA, lds);
    if (threadIdx.x == 0) atomAddF(A, tot);
}

// K2: per-1024-chunk partial sums of S.
__global__ __launch_bounds__(256)
void k2_partials(const float* __restrict__ S, float* __restrict__ partials) {
    __shared__ float lds[16];
    const int base = (int)blockIdx.x * 1024;
    float v = 0.f;
    for (int j = (int)threadIdx.x; j < 1024; j += 256) v += S[base + j];
    const float tot = block_reduce_sum(v, lds);
    if (threadIdx.x == 0) partials[blockIdx.x] = tot;
}

// K3: per-chunk inclusive scan of S (+offset), dot with E via log(P) -> B.
__global__ __launch_bounds__(1024)
void k3_scan_dot(const float* __restrict__ S, const float* __restrict__ E,
                 const float* __restrict__ partials, float* __restrict__ Bacc) {
    __shared__ float lds[16];
    __shared__ float wsum[16];
    __shared__ float s_off;
    const int tid  = (int)threadIdx.x;
    const int lane = tid & 63;
    const int wid  = tid >> 6;
    const int base = (int)blockIdx.x * 1024;

    float p = (tid < (int)blockIdx.x) ? partials[tid] : 0.f;
    const float off = block_reduce_sum(p, lds);
    if (tid == 0) s_off = off;
    __syncthreads();
    const float offset = s_off;

    const float x = S[base + tid];
    float s = x;
    #pragma unroll
    for (int d = 1; d < 64; d <<= 1) {
        const float o = __shfl_up(s, d);
        if (lane >= d) s += o;
    }
    if (lane == 63) wsum[wid] = s;
    __syncthreads();
    if (wid == 0) {
        float ws = (lane < 16) ? wsum[lane] : 0.f;
        #pragma unroll
        for (int d = 1; d < 16; d <<= 1) {
            const float o = __shfl_up(ws, d);
            if (lane >= d) ws += o;
        }
        if (lane < 16) wsum[lane] = ws;
    }
    __syncthreads();
    const float incl = s + (wid > 0 ? wsum[wid - 1] : 0.f);
    const float P = offset + incl;

    const float w = E[base + tid];
    const float c = (w != 0.f) ? w * __logf(P) : 0.f;
    const float tot = block_reduce_sum(c, lds);
    if (tid == 0) atomAddF(Bacc, tot);
}

__global__ void k4_final(const float* __restrict__ A, const float* __restrict__ B,
                         float* __restrict__ out, float inv_n) {
    out[0] = -(A[0] - B[0]) * inv_n;
}

extern "C" void kernel_launch(void* const* d_in, const int* in_sizes, int n_in,
                              void* d_out, int out_size, void* d_ws, size_t ws_size,
                              hipStream_t stream) {
    const float* risk = (const float*)d_in[0];
    const float* ev   = (const float*)d_in[1];
    const int*   tim  = (const int*)d_in[2];
    float* out = (float*)d_out;
    const int n = in_sizes[0];

    // workspace layout (floats): S[NPAD] | E[NPAD] | partials[128] | A | B
    float* S        = (float*)d_ws;
    float* E        = S + NPAD;
    float* partials = E + NPAD;
    float* A        = partials + 128;
    float* B        = A + 1;

    hipMemsetAsync(d_ws, 0, (size_t)(2 * NPAD + 130) * sizeof(float), stream);

    const int blocks = 2048, threads = 256;
    const int win = threads * VPT;                     // 2048 elements per block-iter
    int per_block = (n + blocks - 1) / blocks;
    per_block = ((per_block + win - 1) / win) * win;   // window-aligned

    hipLaunchKernelGGL(k1_bucket, dim3(blocks), dim3(threads), 0, stream,
                       risk, ev, tim, S, E, A, n, per_block);
    hipLaunchKernelGGL(k2_partials, dim3(NBLK_SC), dim3(256), 0, stream, S, partials);
    hipLaunchKernelGGL(k3_scan_dot, dim3(NBLK_SC), dim3(1024), 0, stream, S, E, partials, B);
    hipLaunchKernelGGL(k4_final, dim3(1), dim3(1), 0, stream, A, B, out, 1.0f / (float)n);
}